// Round 1
// baseline (7027.576 us; speedup 1.0000x reference)
//
#include <hip/hip_runtime.h>
#include <hip/hip_bf16.h>

// GCN 3-layer: x(N,12) -> 64 -> 128 -> 96, symmetric-normalized adjacency
// with self loops. N=100000, E=1600000.
//
// Pipeline per layer L with weights W,b and feature width F:
//   hw  = h @ W                         (transform kernel, W staged in LDS)
//   agg = hw * dinv^2 + b               (self-loop + bias, no atomics)
//   agg[dst] += hw[src]*dinv[s]*dinv[d] (edge kernel, fp32 atomics)
//   next h = relu(agg)                  (relu fused into next transform's load)

static inline int cdiv(int a, int b) { return (a + b - 1) / b; }

constexpr int BLOCK = 256;

__global__ void deg_init_kernel(int* __restrict__ deg, int N) {
    int i = blockIdx.x * blockDim.x + threadIdx.x;
    if (i < N) deg[i] = 1;  // self loop
}

__global__ void deg_count_kernel(const int* __restrict__ dst, int E, int* __restrict__ deg) {
    int e = blockIdx.x * blockDim.x + threadIdx.x;
    if (e < E) atomicAdd(&deg[dst[e]], 1);
}

__global__ void dinv_kernel(const int* __restrict__ deg, float* __restrict__ dinv, int N) {
    int i = blockIdx.x * blockDim.x + threadIdx.x;
    if (i < N) dinv[i] = rsqrtf((float)deg[i]);
}

// hw[row, col] = sum_k relu?(h[row,k]) * W[k,col]
template <int IN, int OUT, bool RELU_IN>
__global__ void transform_kernel(const float* __restrict__ h, const float* __restrict__ W,
                                 float* __restrict__ hw, int N) {
    __shared__ float Ws[IN * OUT];
    for (int i = threadIdx.x; i < IN * OUT; i += blockDim.x) Ws[i] = W[i];
    __syncthreads();
    int t = blockIdx.x * blockDim.x + threadIdx.x;
    int total = N * OUT;
    if (t >= total) return;
    int row = t / OUT;
    int col = t - row * OUT;
    const float* __restrict__ hr = h + row * IN;
    float acc = 0.f;
#pragma unroll
    for (int k = 0; k < IN; ++k) {
        float v = hr[k];
        if (RELU_IN) v = fmaxf(v, 0.f);
        acc = fmaf(v, Ws[k * OUT + col], acc);
    }
    hw[t] = acc;
}

// agg[i,f] = hw[i,f]*dinv[i]^2 + b[f]   (self-loop term + bias)
template <int F>
__global__ void agg_init_kernel(const float* __restrict__ hw, const float* __restrict__ dinv,
                                const float* __restrict__ b, float* __restrict__ agg, int N) {
    int t = blockIdx.x * blockDim.x + threadIdx.x;
    int total = N * F;
    if (t >= total) return;
    int row = t / F;
    int col = t - row * F;
    float di = dinv[row];
    agg[t] = fmaf(hw[t], di * di, b[col]);
}

// one thread per (edge, 4-feature chunk): agg[dst] += hw[src] * dinv[s]*dinv[d]
template <int F>
__global__ void edge_agg_kernel(const int* __restrict__ ei, int E,
                                const float* __restrict__ dinv,
                                const float* __restrict__ hw, float* __restrict__ agg) {
    constexpr int CPE = F / 4;  // float4 chunks per edge
    int t = blockIdx.x * blockDim.x + threadIdx.x;
    int total = E * CPE;  // max 51.2M, fits int
    if (t >= total) return;
    int e = t / CPE;
    int c = t - e * CPE;
    int s = ei[e];
    int d = ei[E + e];
    float norm = dinv[s] * dinv[d];
    const float4 v = *(const float4*)(hw + (size_t)s * F + c * 4);
    float* out = agg + (size_t)d * F + c * 4;
    atomicAdd(out + 0, v.x * norm);
    atomicAdd(out + 1, v.y * norm);
    atomicAdd(out + 2, v.z * norm);
    atomicAdd(out + 3, v.w * norm);
}

extern "C" void kernel_launch(void* const* d_in, const int* in_sizes, int n_in,
                              void* d_out, int out_size, void* d_ws, size_t ws_size,
                              hipStream_t stream) {
    const float* x   = (const float*)d_in[0];
    const int*   ei  = (const int*)d_in[1];   // (2,E): row0=src, row1=dst
    const float* W1  = (const float*)d_in[2];
    const float* b1  = (const float*)d_in[3];
    const float* W2  = (const float*)d_in[4];
    const float* b2  = (const float*)d_in[5];
    const float* W3  = (const float*)d_in[6];
    const float* b3  = (const float*)d_in[7];
    float* out = (float*)d_out;

    const int N = in_sizes[0] / 12;
    const int E = in_sizes[1] / 2;

    // workspace layout
    char* ws = (char*)d_ws;
    int*   deg  = (int*)ws;                          ws += (size_t)N * sizeof(int);
    float* dinv = (float*)ws;                        ws += (size_t)N * sizeof(float);
    float* bufA = (float*)ws;                        ws += (size_t)N * 128 * sizeof(float);
    float* bufB = (float*)ws;

    // degree + norm
    deg_init_kernel<<<cdiv(N, BLOCK), BLOCK, 0, stream>>>(deg, N);
    deg_count_kernel<<<cdiv(E, BLOCK), BLOCK, 0, stream>>>(ei + E, E, deg);
    dinv_kernel<<<cdiv(N, BLOCK), BLOCK, 0, stream>>>(deg, dinv, N);

    // ---- layer 1: 12 -> 64 ----
    transform_kernel<12, 64, false><<<cdiv(N * 64, BLOCK), BLOCK, 0, stream>>>(x, W1, bufA, N);
    agg_init_kernel<64><<<cdiv(N * 64, BLOCK), BLOCK, 0, stream>>>(bufA, dinv, b1, bufB, N);
    edge_agg_kernel<64><<<cdiv(E * 16, BLOCK), BLOCK, 0, stream>>>(ei, E, dinv, bufA, bufB);

    // ---- layer 2: 64 -> 128 ----  (relu on load of bufB)
    transform_kernel<64, 128, true><<<cdiv(N * 128, BLOCK), BLOCK, 0, stream>>>(bufB, W2, bufA, N);
    agg_init_kernel<128><<<cdiv(N * 128, BLOCK), BLOCK, 0, stream>>>(bufA, dinv, b2, bufB, N);
    edge_agg_kernel<128><<<cdiv(E * 32, BLOCK), BLOCK, 0, stream>>>(ei, E, dinv, bufA, bufB);

    // ---- layer 3: 128 -> 96 ----  (relu on load, write d_out directly)
    transform_kernel<128, 96, true><<<cdiv(N * 96, BLOCK), BLOCK, 0, stream>>>(bufB, W3, bufA, N);
    agg_init_kernel<96><<<cdiv(N * 96, BLOCK), BLOCK, 0, stream>>>(bufA, dinv, b3, out, N);
    edge_agg_kernel<96><<<cdiv(E * 24, BLOCK), BLOCK, 0, stream>>>(ei, E, dinv, bufA, out);
}

// Round 2
// 1363.712 us; speedup vs baseline: 5.1533x; 5.1533x over previous
//
#include <hip/hip_runtime.h>
#include <hip/hip_bf16.h>

// GCN 3-layer: x(N,12) -> 64 -> 128 -> 96, symmetric normalization + self loops.
// N=100000, E=1600000.
//
// R2: replace fp32-atomic scatter aggregation (atomic-bound, VALUBusy 1.4%)
// with CSR build (counting sort by dst) + pull-style register-accumulated
// gather. Self-loop + bias fused into the gather epilogue.

static inline int cdiv(int a, int b) { return (a + b - 1) / b; }
constexpr int BLOCK = 256;

// ---------------- CSR build ----------------

__global__ void zero_int_kernel(int* __restrict__ p, int n) {
    int i = blockIdx.x * blockDim.x + threadIdx.x;
    if (i < n) p[i] = 0;
}

__global__ void hist_kernel(const int* __restrict__ dst, int E, int* __restrict__ deg) {
    int e = blockIdx.x * blockDim.x + threadIdx.x;
    if (e < E) atomicAdd(&deg[dst[e]], 1);
}

// dinv includes the self loop: deg_norm = indeg + 1
__global__ void dinv_kernel(const int* __restrict__ deg, float* __restrict__ dinv, int N) {
    int i = blockIdx.x * blockDim.x + threadIdx.x;
    if (i < N) dinv[i] = rsqrtf((float)deg[i] + 1.0f);
}

// per-block exclusive scan (Hillis-Steele in LDS), emit block sums
__global__ void scan_block_kernel(const int* __restrict__ deg, int* __restrict__ row_ptr,
                                  int* __restrict__ bsum, int N) {
    __shared__ int tmp[BLOCK];
    int i = blockIdx.x * BLOCK + threadIdx.x;
    int v = (i < N) ? deg[i] : 0;
    tmp[threadIdx.x] = v;
    __syncthreads();
    for (int off = 1; off < BLOCK; off <<= 1) {
        int add = (threadIdx.x >= off) ? tmp[threadIdx.x - off] : 0;
        __syncthreads();
        tmp[threadIdx.x] += add;
        __syncthreads();
    }
    if (i < N) row_ptr[i] = tmp[threadIdx.x] - v;  // exclusive
    if (threadIdx.x == BLOCK - 1) bsum[blockIdx.x] = tmp[BLOCK - 1];
}

// single-block exclusive scan of block sums (nb <= 1024)
__global__ void scan_sums_kernel(int* __restrict__ bsum, int nb) {
    __shared__ int tmp[1024];
    int v = (threadIdx.x < nb) ? bsum[threadIdx.x] : 0;
    tmp[threadIdx.x] = v;
    __syncthreads();
    for (int off = 1; off < 1024; off <<= 1) {
        int add = (threadIdx.x >= off) ? tmp[threadIdx.x - off] : 0;
        __syncthreads();
        tmp[threadIdx.x] += add;
        __syncthreads();
    }
    if (threadIdx.x < nb) bsum[threadIdx.x] = tmp[threadIdx.x] - v;
}

__global__ void finalize_scan_kernel(int* __restrict__ row_ptr, const int* __restrict__ bsum,
                                     int* __restrict__ cursor, int N) {
    int i = blockIdx.x * BLOCK + threadIdx.x;
    if (i < N) {
        int r = row_ptr[i] + bsum[blockIdx.x];
        row_ptr[i] = r;
        cursor[i] = r;
    }
}

__global__ void scatter_kernel(const int* __restrict__ ei, int E,
                               int* __restrict__ cursor, int* __restrict__ csr_src) {
    int e = blockIdx.x * blockDim.x + threadIdx.x;
    if (e >= E) return;
    int s = ei[e];
    int d = ei[E + e];
    int pos = atomicAdd(&cursor[d], 1);
    csr_src[pos] = s;
}

// ---------------- dense transform ----------------

// hw[row, col] = sum_k relu?(h[row,k]) * W[k,col], W staged in LDS
template <int IN, int OUT, bool RELU_IN>
__global__ void transform_kernel(const float* __restrict__ h, const float* __restrict__ W,
                                 float* __restrict__ hw, int N) {
    __shared__ float Ws[IN * OUT];
    for (int i = threadIdx.x; i < IN * OUT; i += blockDim.x) Ws[i] = W[i];
    __syncthreads();
    int t = blockIdx.x * blockDim.x + threadIdx.x;
    int total = N * OUT;
    if (t >= total) return;
    int row = t / OUT;
    int col = t - row * OUT;
    const float* __restrict__ hr = h + (size_t)row * IN;
    float acc = 0.f;
#pragma unroll
    for (int k = 0; k < IN; ++k) {
        float v = hr[k];
        if (RELU_IN) v = fmaxf(v, 0.f);
        acc = fmaf(v, Ws[k * OUT + col], acc);
    }
    hw[t] = acc;
}

// ---------------- pull gather ----------------

// out[i, f0:f0+4] = dinv[i] * sum_{e in CSR[i]} dinv[src_e] * hw[src_e, f0:f0+4]
//                 + dinv[i]^2 * hw[i, f0:f0+4] + b[f0:f0+4]
template <int F>
__global__ void gather_kernel(const int* __restrict__ row_ptr, const int* __restrict__ deg,
                              const int* __restrict__ csr_src, const float* __restrict__ dinv,
                              const float* __restrict__ hw, const float* __restrict__ b,
                              float* __restrict__ out, int N) {
    constexpr int TPN = F / 4;  // threads per node
    int t = blockIdx.x * blockDim.x + threadIdx.x;
    if (t >= N * TPN) return;
    int i = t / TPN;
    int c = t - i * TPN;
    int f0 = c * 4;

    float di = dinv[i];
    const float4 self = *(const float4*)(hw + (size_t)i * F + f0);

    float4 acc = make_float4(0.f, 0.f, 0.f, 0.f);
    int start = row_ptr[i];
    int n = deg[i];
    for (int k = 0; k < n; ++k) {
        int s = csr_src[start + k];
        float ds = dinv[s];
        const float4 v = *(const float4*)(hw + (size_t)s * F + f0);
        acc.x = fmaf(v.x, ds, acc.x);
        acc.y = fmaf(v.y, ds, acc.y);
        acc.z = fmaf(v.z, ds, acc.z);
        acc.w = fmaf(v.w, ds, acc.w);
    }
    float di2 = di * di;
    float4 r;
    r.x = fmaf(acc.x, di, fmaf(self.x, di2, b[f0 + 0]));
    r.y = fmaf(acc.y, di, fmaf(self.y, di2, b[f0 + 1]));
    r.z = fmaf(acc.z, di, fmaf(self.z, di2, b[f0 + 2]));
    r.w = fmaf(acc.w, di, fmaf(self.w, di2, b[f0 + 3]));
    *(float4*)(out + (size_t)i * F + f0) = r;
}

// ---------------- launch ----------------

extern "C" void kernel_launch(void* const* d_in, const int* in_sizes, int n_in,
                              void* d_out, int out_size, void* d_ws, size_t ws_size,
                              hipStream_t stream) {
    const float* x  = (const float*)d_in[0];
    const int*   ei = (const int*)d_in[1];  // (2,E): row0=src, row1=dst
    const float* W1 = (const float*)d_in[2];
    const float* b1 = (const float*)d_in[3];
    const float* W2 = (const float*)d_in[4];
    const float* b2 = (const float*)d_in[5];
    const float* W3 = (const float*)d_in[6];
    const float* b3 = (const float*)d_in[7];
    float* out = (float*)d_out;

    const int N = in_sizes[0] / 12;
    const int E = in_sizes[1] / 2;
    const int nb = cdiv(N, BLOCK);  // 391 scan blocks (<=1024)

    // workspace layout
    char* ws = (char*)d_ws;
    int*   deg     = (int*)ws;    ws += (size_t)N * sizeof(int);
    int*   row_ptr = (int*)ws;    ws += (size_t)N * sizeof(int);
    int*   cursor  = (int*)ws;    ws += (size_t)N * sizeof(int);
    int*   bsum    = (int*)ws;    ws += 1024 * sizeof(int);
    float* dinv    = (float*)ws;  ws += (size_t)N * sizeof(float);
    int*   csr_src = (int*)ws;    ws += (size_t)E * sizeof(int);
    float* bufA    = (float*)ws;  ws += (size_t)N * 128 * sizeof(float);
    float* bufB    = (float*)ws;

    // ---- CSR build (shared across layers) ----
    zero_int_kernel<<<nb, BLOCK, 0, stream>>>(deg, N);
    hist_kernel<<<cdiv(E, BLOCK), BLOCK, 0, stream>>>(ei + E, E, deg);
    dinv_kernel<<<nb, BLOCK, 0, stream>>>(deg, dinv, N);
    scan_block_kernel<<<nb, BLOCK, 0, stream>>>(deg, row_ptr, bsum, N);
    scan_sums_kernel<<<1, 1024, 0, stream>>>(bsum, nb);
    finalize_scan_kernel<<<nb, BLOCK, 0, stream>>>(row_ptr, bsum, cursor, N);
    scatter_kernel<<<cdiv(E, BLOCK), BLOCK, 0, stream>>>(ei, E, cursor, csr_src);

    // ---- layer 1: 12 -> 64 ----
    transform_kernel<12, 64, false><<<cdiv(N * 64, BLOCK), BLOCK, 0, stream>>>(x, W1, bufA, N);
    gather_kernel<64><<<cdiv(N * 16, BLOCK), BLOCK, 0, stream>>>(row_ptr, deg, csr_src, dinv,
                                                                 bufA, b1, bufB, N);

    // ---- layer 2: 64 -> 128 ---- (relu fused into transform load)
    transform_kernel<64, 128, true><<<cdiv(N * 128, BLOCK), BLOCK, 0, stream>>>(bufB, W2, bufA, N);
    gather_kernel<128><<<cdiv(N * 32, BLOCK), BLOCK, 0, stream>>>(row_ptr, deg, csr_src, dinv,
                                                                  bufA, b2, bufB, N);

    // ---- layer 3: 128 -> 96 ---- (relu fused, gather writes d_out)
    transform_kernel<128, 96, true><<<cdiv(N * 96, BLOCK), BLOCK, 0, stream>>>(bufB, W3, bufA, N);
    gather_kernel<96><<<cdiv(N * 24, BLOCK), BLOCK, 0, stream>>>(row_ptr, deg, csr_src, dinv,
                                                                 bufA, b3, out, N);
}

// Round 3
// 693.040 us; speedup vs baseline: 10.1402x; 1.9677x over previous
//
#include <hip/hip_runtime.h>
#include <hip/hip_bf16.h>

// GCN 3-layer: x(N,12) -> 64 -> 128 -> 96, symmetric normalization + self loops.
// N=100000, E=1600000.
//
// R2: CSR + pull-gather (replaced atomic scatter; 7028 -> 1364 us).
// R3: register-tiled transform: 4x4 microtile per thread, float4 global h
//     loads + float4 LDS W loads. Replaces 1-elem-per-thread scalar-load
//     transform (488 us @ VALUBusy 34% for layer 3).

static inline int cdiv(int a, int b) { return (a + b - 1) / b; }
constexpr int BLOCK = 256;

// ---------------- CSR build ----------------

__global__ void zero_int_kernel(int* __restrict__ p, int n) {
    int i = blockIdx.x * blockDim.x + threadIdx.x;
    if (i < n) p[i] = 0;
}

__global__ void hist_kernel(const int* __restrict__ dst, int E, int* __restrict__ deg) {
    int e = blockIdx.x * blockDim.x + threadIdx.x;
    if (e < E) atomicAdd(&deg[dst[e]], 1);
}

// dinv includes the self loop: deg_norm = indeg + 1
__global__ void dinv_kernel(const int* __restrict__ deg, float* __restrict__ dinv, int N) {
    int i = blockIdx.x * blockDim.x + threadIdx.x;
    if (i < N) dinv[i] = rsqrtf((float)deg[i] + 1.0f);
}

// per-block exclusive scan (Hillis-Steele in LDS), emit block sums
__global__ void scan_block_kernel(const int* __restrict__ deg, int* __restrict__ row_ptr,
                                  int* __restrict__ bsum, int N) {
    __shared__ int tmp[BLOCK];
    int i = blockIdx.x * BLOCK + threadIdx.x;
    int v = (i < N) ? deg[i] : 0;
    tmp[threadIdx.x] = v;
    __syncthreads();
    for (int off = 1; off < BLOCK; off <<= 1) {
        int add = (threadIdx.x >= off) ? tmp[threadIdx.x - off] : 0;
        __syncthreads();
        tmp[threadIdx.x] += add;
        __syncthreads();
    }
    if (i < N) row_ptr[i] = tmp[threadIdx.x] - v;  // exclusive
    if (threadIdx.x == BLOCK - 1) bsum[blockIdx.x] = tmp[BLOCK - 1];
}

// single-block exclusive scan of block sums (nb <= 1024)
__global__ void scan_sums_kernel(int* __restrict__ bsum, int nb) {
    __shared__ int tmp[1024];
    int v = (threadIdx.x < nb) ? bsum[threadIdx.x] : 0;
    tmp[threadIdx.x] = v;
    __syncthreads();
    for (int off = 1; off < 1024; off <<= 1) {
        int add = (threadIdx.x >= off) ? tmp[threadIdx.x - off] : 0;
        __syncthreads();
        tmp[threadIdx.x] += add;
        __syncthreads();
    }
    if (threadIdx.x < nb) bsum[threadIdx.x] = tmp[threadIdx.x] - v;
}

__global__ void finalize_scan_kernel(int* __restrict__ row_ptr, const int* __restrict__ bsum,
                                     int* __restrict__ cursor, int N) {
    int i = blockIdx.x * BLOCK + threadIdx.x;
    if (i < N) {
        int r = row_ptr[i] + bsum[blockIdx.x];
        row_ptr[i] = r;
        cursor[i] = r;
    }
}

__global__ void scatter_kernel(const int* __restrict__ ei, int E,
                               int* __restrict__ cursor, int* __restrict__ csr_src) {
    int e = blockIdx.x * blockDim.x + threadIdx.x;
    if (e >= E) return;
    int s = ei[e];
    int d = ei[E + e];
    int pos = atomicAdd(&cursor[d], 1);
    csr_src[pos] = s;
}

// ---------------- dense transform (register-tiled) ----------------

__device__ __forceinline__ void fma4(float4& acc, float s, const float4& w) {
    acc.x = fmaf(s, w.x, acc.x);
    acc.y = fmaf(s, w.y, acc.y);
    acc.z = fmaf(s, w.z, acc.z);
    acc.w = fmaf(s, w.w, acc.w);
}

// Each thread computes a 4-row x 4-col microtile of hw = relu?(h) @ W.
// Block covers 32 rows x OUT cols; THREADS = 8 * (OUT/4).
template <int IN, int OUT, bool RELU_IN>
__global__ void transform_kernel(const float* __restrict__ h, const float* __restrict__ W,
                                 float* __restrict__ hw, int N) {
    constexpr int CG = OUT / 4;        // col groups
    constexpr int THREADS = 8 * CG;    // 8 row groups of 4 rows
    __shared__ float Ws[IN * OUT];
    for (int i = threadIdx.x; i < IN * OUT / 4; i += THREADS)
        ((float4*)Ws)[i] = ((const float4*)W)[i];
    __syncthreads();

    const int c0 = (threadIdx.x % CG) * 4;
    const int r0 = blockIdx.x * 32 + (threadIdx.x / CG) * 4;
    if (r0 >= N) return;  // N % 32 == 0, so full 4-row groups only

    const float* __restrict__ hr = h + (size_t)r0 * IN;
    float4 acc[4];
#pragma unroll
    for (int i = 0; i < 4; ++i) acc[i] = make_float4(0.f, 0.f, 0.f, 0.f);

#pragma unroll
    for (int k = 0; k < IN; k += 4) {
        float4 a[4];
#pragma unroll
        for (int i = 0; i < 4; ++i) {
            a[i] = *(const float4*)(hr + (size_t)i * IN + k);
            if (RELU_IN) {
                a[i].x = fmaxf(a[i].x, 0.f);
                a[i].y = fmaxf(a[i].y, 0.f);
                a[i].z = fmaxf(a[i].z, 0.f);
                a[i].w = fmaxf(a[i].w, 0.f);
            }
        }
        const float4 w0 = *(const float4*)(Ws + (k + 0) * OUT + c0);
        const float4 w1 = *(const float4*)(Ws + (k + 1) * OUT + c0);
        const float4 w2 = *(const float4*)(Ws + (k + 2) * OUT + c0);
        const float4 w3 = *(const float4*)(Ws + (k + 3) * OUT + c0);
#pragma unroll
        for (int i = 0; i < 4; ++i) {
            fma4(acc[i], a[i].x, w0);
            fma4(acc[i], a[i].y, w1);
            fma4(acc[i], a[i].z, w2);
            fma4(acc[i], a[i].w, w3);
        }
    }

#pragma unroll
    for (int i = 0; i < 4; ++i)
        *(float4*)(hw + (size_t)(r0 + i) * OUT + c0) = acc[i];
}

// ---------------- pull gather ----------------

// out[i, f0:f0+4] = dinv[i] * sum_{e in CSR[i]} dinv[src_e] * hw[src_e, f0:f0+4]
//                 + dinv[i]^2 * hw[i, f0:f0+4] + b[f0:f0+4]
template <int F>
__global__ void gather_kernel(const int* __restrict__ row_ptr, const int* __restrict__ deg,
                              const int* __restrict__ csr_src, const float* __restrict__ dinv,
                              const float* __restrict__ hw, const float* __restrict__ b,
                              float* __restrict__ out, int N) {
    constexpr int TPN = F / 4;  // threads per node
    int t = blockIdx.x * blockDim.x + threadIdx.x;
    if (t >= N * TPN) return;
    int i = t / TPN;
    int c = t - i * TPN;
    int f0 = c * 4;

    float di = dinv[i];
    const float4 self = *(const float4*)(hw + (size_t)i * F + f0);

    float4 acc = make_float4(0.f, 0.f, 0.f, 0.f);
    int start = row_ptr[i];
    int n = deg[i];
    for (int k = 0; k < n; ++k) {
        int s = csr_src[start + k];
        float ds = dinv[s];
        const float4 v = *(const float4*)(hw + (size_t)s * F + f0);
        acc.x = fmaf(v.x, ds, acc.x);
        acc.y = fmaf(v.y, ds, acc.y);
        acc.z = fmaf(v.z, ds, acc.z);
        acc.w = fmaf(v.w, ds, acc.w);
    }
    float di2 = di * di;
    float4 r;
    r.x = fmaf(acc.x, di, fmaf(self.x, di2, b[f0 + 0]));
    r.y = fmaf(acc.y, di, fmaf(self.y, di2, b[f0 + 1]));
    r.z = fmaf(acc.z, di, fmaf(self.z, di2, b[f0 + 2]));
    r.w = fmaf(acc.w, di, fmaf(self.w, di2, b[f0 + 3]));
    *(float4*)(out + (size_t)i * F + f0) = r;
}

// ---------------- launch ----------------

extern "C" void kernel_launch(void* const* d_in, const int* in_sizes, int n_in,
                              void* d_out, int out_size, void* d_ws, size_t ws_size,
                              hipStream_t stream) {
    const float* x  = (const float*)d_in[0];
    const int*   ei = (const int*)d_in[1];  // (2,E): row0=src, row1=dst
    const float* W1 = (const float*)d_in[2];
    const float* b1 = (const float*)d_in[3];
    const float* W2 = (const float*)d_in[4];
    const float* b2 = (const float*)d_in[5];
    const float* W3 = (const float*)d_in[6];
    const float* b3 = (const float*)d_in[7];
    float* out = (float*)d_out;

    const int N = in_sizes[0] / 12;
    const int E = in_sizes[1] / 2;
    const int nb = cdiv(N, BLOCK);  // 391 scan blocks (<=1024)

    // workspace layout
    char* ws = (char*)d_ws;
    int*   deg     = (int*)ws;    ws += (size_t)N * sizeof(int);
    int*   row_ptr = (int*)ws;    ws += (size_t)N * sizeof(int);
    int*   cursor  = (int*)ws;    ws += (size_t)N * sizeof(int);
    int*   bsum    = (int*)ws;    ws += 1024 * sizeof(int);
    float* dinv    = (float*)ws;  ws += (size_t)N * sizeof(float);
    int*   csr_src = (int*)ws;    ws += (size_t)E * sizeof(int);
    float* bufA    = (float*)ws;  ws += (size_t)N * 128 * sizeof(float);
    float* bufB    = (float*)ws;

    // ---- CSR build (shared across layers) ----
    zero_int_kernel<<<nb, BLOCK, 0, stream>>>(deg, N);
    hist_kernel<<<cdiv(E, BLOCK), BLOCK, 0, stream>>>(ei + E, E, deg);
    dinv_kernel<<<nb, BLOCK, 0, stream>>>(deg, dinv, N);
    scan_block_kernel<<<nb, BLOCK, 0, stream>>>(deg, row_ptr, bsum, N);
    scan_sums_kernel<<<1, 1024, 0, stream>>>(bsum, nb);
    finalize_scan_kernel<<<nb, BLOCK, 0, stream>>>(row_ptr, bsum, cursor, N);
    scatter_kernel<<<cdiv(E, BLOCK), BLOCK, 0, stream>>>(ei, E, cursor, csr_src);

    const int tb = cdiv(N, 32);  // 3125 transform blocks

    // ---- layer 1: 12 -> 64 ----
    transform_kernel<12, 64, false><<<tb, 8 * (64 / 4), 0, stream>>>(x, W1, bufA, N);
    gather_kernel<64><<<cdiv(N * 16, BLOCK), BLOCK, 0, stream>>>(row_ptr, deg, csr_src, dinv,
                                                                 bufA, b1, bufB, N);

    // ---- layer 2: 64 -> 128 ---- (relu fused into transform load)
    transform_kernel<64, 128, true><<<tb, 8 * (128 / 4), 0, stream>>>(bufB, W2, bufA, N);
    gather_kernel<128><<<cdiv(N * 32, BLOCK), BLOCK, 0, stream>>>(row_ptr, deg, csr_src, dinv,
                                                                  bufA, b2, bufB, N);

    // ---- layer 3: 128 -> 96 ---- (relu fused, gather writes d_out)
    transform_kernel<128, 96, true><<<tb, 8 * (96 / 4), 0, stream>>>(bufB, W3, bufA, N);
    gather_kernel<96><<<cdiv(N * 24, BLOCK), BLOCK, 0, stream>>>(row_ptr, deg, csr_src, dinv,
                                                                 bufA, b3, out, N);
}

// Round 4
// 549.823 us; speedup vs baseline: 12.7815x; 1.2605x over previous
//
#include <hip/hip_runtime.h>
#include <hip/hip_bf16.h>

// GCN 3-layer: x(N,12) -> 64 -> 128 -> 96, symmetric normalization + self loops.
// N=100000, E=1600000.
//
// R2: CSR + pull-gather (7028 -> 1364 us).
// R3: register-tiled 4x4-microtile transform (1364 -> 693 us).
// R4: associativity reorder — aggregate at min(IN,OUT) width per layer
//     (12/64/96 instead of 64/128/96); pre-scale rows by dinv[src] in the
//     producer epilogue so the gather loop is index->float4->add only.

static inline int cdiv(int a, int b) { return (a + b - 1) / b; }
constexpr int BLOCK = 256;

// ---------------- CSR build ----------------

__global__ void zero_int_kernel(int* __restrict__ p, int n) {
    int i = blockIdx.x * blockDim.x + threadIdx.x;
    if (i < n) p[i] = 0;
}

__global__ void hist_kernel(const int* __restrict__ dst, int E, int* __restrict__ deg) {
    int e = blockIdx.x * blockDim.x + threadIdx.x;
    if (e < E) atomicAdd(&deg[dst[e]], 1);
}

// dinv includes the self loop: deg_norm = indeg + 1
__global__ void dinv_kernel(const int* __restrict__ deg, float* __restrict__ dinv, int N) {
    int i = blockIdx.x * blockDim.x + threadIdx.x;
    if (i < N) dinv[i] = rsqrtf((float)deg[i] + 1.0f);
}

// per-block exclusive scan (Hillis-Steele in LDS), emit block sums
__global__ void scan_block_kernel(const int* __restrict__ deg, int* __restrict__ row_ptr,
                                  int* __restrict__ bsum, int N) {
    __shared__ int tmp[BLOCK];
    int i = blockIdx.x * BLOCK + threadIdx.x;
    int v = (i < N) ? deg[i] : 0;
    tmp[threadIdx.x] = v;
    __syncthreads();
    for (int off = 1; off < BLOCK; off <<= 1) {
        int add = (threadIdx.x >= off) ? tmp[threadIdx.x - off] : 0;
        __syncthreads();
        tmp[threadIdx.x] += add;
        __syncthreads();
    }
    if (i < N) row_ptr[i] = tmp[threadIdx.x] - v;  // exclusive
    if (threadIdx.x == BLOCK - 1) bsum[blockIdx.x] = tmp[BLOCK - 1];
}

// single-block exclusive scan of block sums (nb <= 1024)
__global__ void scan_sums_kernel(int* __restrict__ bsum, int nb) {
    __shared__ int tmp[1024];
    int v = (threadIdx.x < nb) ? bsum[threadIdx.x] : 0;
    tmp[threadIdx.x] = v;
    __syncthreads();
    for (int off = 1; off < 1024; off <<= 1) {
        int add = (threadIdx.x >= off) ? tmp[threadIdx.x - off] : 0;
        __syncthreads();
        tmp[threadIdx.x] += add;
        __syncthreads();
    }
    if (threadIdx.x < nb) bsum[threadIdx.x] = tmp[threadIdx.x] - v;
}

__global__ void finalize_scan_kernel(int* __restrict__ row_ptr, const int* __restrict__ bsum,
                                     int* __restrict__ cursor, int N) {
    int i = blockIdx.x * BLOCK + threadIdx.x;
    if (i < N) {
        int r = row_ptr[i] + bsum[blockIdx.x];
        row_ptr[i] = r;
        cursor[i] = r;
    }
}

__global__ void scatter_kernel(const int* __restrict__ ei, int E,
                               int* __restrict__ cursor, int* __restrict__ csr_src) {
    int e = blockIdx.x * blockDim.x + threadIdx.x;
    if (e >= E) return;
    int s = ei[e];
    int d = ei[E + e];
    int pos = atomicAdd(&cursor[d], 1);
    csr_src[pos] = s;
}

// xs[i,:] = x[i,:] * dinv[i]   (F=12: 3 float4 chunks per row)
__global__ void prescale_kernel(const float* __restrict__ x, const float* __restrict__ dinv,
                                float* __restrict__ xs, int N) {
    int t = blockIdx.x * blockDim.x + threadIdx.x;
    if (t >= N * 3) return;
    int i = t / 3;
    float di = dinv[i];
    float4 v = ((const float4*)x)[t];
    v.x *= di; v.y *= di; v.z *= di; v.w *= di;
    ((float4*)xs)[t] = v;
}

// ---------------- dense transform (register-tiled) ----------------

__device__ __forceinline__ void fma4(float4& acc, float s, const float4& w) {
    acc.x = fmaf(s, w.x, acc.x);
    acc.y = fmaf(s, w.y, acc.y);
    acc.z = fmaf(s, w.z, acc.z);
    acc.w = fmaf(s, w.w, acc.w);
}

// Each thread computes a 4-row x 4-col microtile of out = h @ W, with
// optional epilogue: +bias, relu, *dinv[row]. Block covers 32 rows x OUT.
template <int IN, int OUT, bool HAS_BIAS, bool RELU, bool SCALE>
__global__ void transform_kernel(const float* __restrict__ h, const float* __restrict__ W,
                                 const float* __restrict__ bias, const float* __restrict__ dinv,
                                 float* __restrict__ out, int N) {
    constexpr int CG = OUT / 4;        // col groups
    constexpr int THREADS = 8 * CG;    // 8 row groups of 4 rows
    __shared__ float Ws[IN * OUT];
    for (int i = threadIdx.x; i < IN * OUT / 4; i += THREADS)
        ((float4*)Ws)[i] = ((const float4*)W)[i];
    __syncthreads();

    const int c0 = (threadIdx.x % CG) * 4;
    const int r0 = blockIdx.x * 32 + (threadIdx.x / CG) * 4;
    if (r0 >= N) return;  // N % 32 == 0

    const float* __restrict__ hr = h + (size_t)r0 * IN;
    float4 acc[4];
#pragma unroll
    for (int i = 0; i < 4; ++i) acc[i] = make_float4(0.f, 0.f, 0.f, 0.f);

#pragma unroll
    for (int k = 0; k < IN; k += 4) {
        float4 a[4];
#pragma unroll
        for (int i = 0; i < 4; ++i) a[i] = *(const float4*)(hr + (size_t)i * IN + k);
        const float4 w0 = *(const float4*)(Ws + (k + 0) * OUT + c0);
        const float4 w1 = *(const float4*)(Ws + (k + 1) * OUT + c0);
        const float4 w2 = *(const float4*)(Ws + (k + 2) * OUT + c0);
        const float4 w3 = *(const float4*)(Ws + (k + 3) * OUT + c0);
#pragma unroll
        for (int i = 0; i < 4; ++i) {
            fma4(acc[i], a[i].x, w0);
            fma4(acc[i], a[i].y, w1);
            fma4(acc[i], a[i].z, w2);
            fma4(acc[i], a[i].w, w3);
        }
    }

    float4 bb = make_float4(0.f, 0.f, 0.f, 0.f);
    if (HAS_BIAS) bb = *(const float4*)(bias + c0);
#pragma unroll
    for (int i = 0; i < 4; ++i) {
        float4 r = acc[i];
        if (HAS_BIAS) { r.x += bb.x; r.y += bb.y; r.z += bb.z; r.w += bb.w; }
        if (RELU) {
            r.x = fmaxf(r.x, 0.f); r.y = fmaxf(r.y, 0.f);
            r.z = fmaxf(r.z, 0.f); r.w = fmaxf(r.w, 0.f);
        }
        if (SCALE) {
            float di = dinv[r0 + i];
            r.x *= di; r.y *= di; r.z *= di; r.w *= di;
        }
        *(float4*)(out + (size_t)(r0 + i) * OUT + c0) = r;
    }
}

// ---------------- pull gather ----------------

// hws rows are pre-scaled by dinv[src].
// out[i, f0:f0+4] = dinv[i] * (hws[i] + sum_{s in CSR[i]} hws[s]) (+ b)
template <int F, bool HAS_BIAS>
__global__ void gather_kernel(const int* __restrict__ row_ptr, const int* __restrict__ deg,
                              const int* __restrict__ csr_src,
                              const float* __restrict__ dinv, const float* __restrict__ hws,
                              const float* __restrict__ b, float* __restrict__ out, int N) {
    constexpr int TPN = F / 4;  // threads per node
    int t = blockIdx.x * blockDim.x + threadIdx.x;
    if (t >= N * TPN) return;
    int i = t / TPN;
    int c = t - i * TPN;
    int f0 = c * 4;

    const int* __restrict__ sp = csr_src + row_ptr[i];
    int n = deg[i];
    float4 acc = *(const float4*)(hws + (size_t)i * F + f0);  // self loop

    int k = 0;
    for (; k + 4 <= n; k += 4) {
        int s0 = sp[k + 0], s1 = sp[k + 1], s2 = sp[k + 2], s3 = sp[k + 3];
        const float4 v0 = *(const float4*)(hws + (size_t)s0 * F + f0);
        const float4 v1 = *(const float4*)(hws + (size_t)s1 * F + f0);
        const float4 v2 = *(const float4*)(hws + (size_t)s2 * F + f0);
        const float4 v3 = *(const float4*)(hws + (size_t)s3 * F + f0);
        acc.x += (v0.x + v1.x) + (v2.x + v3.x);
        acc.y += (v0.y + v1.y) + (v2.y + v3.y);
        acc.z += (v0.z + v1.z) + (v2.z + v3.z);
        acc.w += (v0.w + v1.w) + (v2.w + v3.w);
    }
    for (; k < n; ++k) {
        int s = sp[k];
        const float4 v = *(const float4*)(hws + (size_t)s * F + f0);
        acc.x += v.x; acc.y += v.y; acc.z += v.z; acc.w += v.w;
    }

    float di = dinv[i];
    float4 r;
    if (HAS_BIAS) {
        const float4 bb = *(const float4*)(b + f0);
        r.x = fmaf(acc.x, di, bb.x);
        r.y = fmaf(acc.y, di, bb.y);
        r.z = fmaf(acc.z, di, bb.z);
        r.w = fmaf(acc.w, di, bb.w);
    } else {
        r.x = acc.x * di; r.y = acc.y * di; r.z = acc.z * di; r.w = acc.w * di;
    }
    *(float4*)(out + (size_t)i * F + f0) = r;
}

// ---------------- launch ----------------

extern "C" void kernel_launch(void* const* d_in, const int* in_sizes, int n_in,
                              void* d_out, int out_size, void* d_ws, size_t ws_size,
                              hipStream_t stream) {
    const float* x  = (const float*)d_in[0];
    const int*   ei = (const int*)d_in[1];  // (2,E): row0=src, row1=dst
    const float* W1 = (const float*)d_in[2];
    const float* b1 = (const float*)d_in[3];
    const float* W2 = (const float*)d_in[4];
    const float* b2 = (const float*)d_in[5];
    const float* W3 = (const float*)d_in[6];
    const float* b3 = (const float*)d_in[7];
    float* out = (float*)d_out;

    const int N = in_sizes[0] / 12;
    const int E = in_sizes[1] / 2;
    const int nb = cdiv(N, BLOCK);

    // workspace layout (ping-pong: A holds pre-gather rows, B holds aggregates)
    char* ws = (char*)d_ws;
    int*   deg     = (int*)ws;    ws += (size_t)N * sizeof(int);
    int*   row_ptr = (int*)ws;    ws += (size_t)N * sizeof(int);
    int*   cursor  = (int*)ws;    ws += (size_t)N * sizeof(int);
    int*   bsum    = (int*)ws;    ws += 1024 * sizeof(int);
    float* dinv    = (float*)ws;  ws += (size_t)N * sizeof(float);
    int*   csr_src = (int*)ws;    ws += (size_t)E * sizeof(int);
    float* bufA    = (float*)ws;  ws += (size_t)N * 128 * sizeof(float);  // xs / h1s / h2
    float* bufB    = (float*)ws;                                          // aggx / agg1 / hw3s

    // ---- CSR build (shared across layers) ----
    zero_int_kernel<<<nb, BLOCK, 0, stream>>>(deg, N);
    hist_kernel<<<cdiv(E, BLOCK), BLOCK, 0, stream>>>(ei + E, E, deg);
    dinv_kernel<<<nb, BLOCK, 0, stream>>>(deg, dinv, N);
    scan_block_kernel<<<nb, BLOCK, 0, stream>>>(deg, row_ptr, bsum, N);
    scan_sums_kernel<<<1, 1024, 0, stream>>>(bsum, nb);
    finalize_scan_kernel<<<nb, BLOCK, 0, stream>>>(row_ptr, bsum, cursor, N);
    scatter_kernel<<<cdiv(E, BLOCK), BLOCK, 0, stream>>>(ei, E, cursor, csr_src);

    const int tb = cdiv(N, 32);  // transform blocks

    // ---- layer 1: aggregate at F=12, then 12->64 (+b1, relu, *dinv) ----
    prescale_kernel<<<cdiv(N * 3, BLOCK), BLOCK, 0, stream>>>(x, dinv, bufA, N);
    gather_kernel<12, false><<<cdiv(N * 3, BLOCK), BLOCK, 0, stream>>>(
        row_ptr, deg, csr_src, dinv, bufA, nullptr, bufB, N);
    transform_kernel<12, 64, true, true, true><<<tb, 8 * (64 / 4), 0, stream>>>(
        bufB, W1, b1, dinv, bufA, N);  // bufA = h1s (scaled)

    // ---- layer 2: aggregate at F=64, then 64->128 (+b2, relu) ----
    gather_kernel<64, false><<<cdiv(N * 16, BLOCK), BLOCK, 0, stream>>>(
        row_ptr, deg, csr_src, dinv, bufA, nullptr, bufB, N);
    transform_kernel<64, 128, true, true, false><<<tb, 8 * (128 / 4), 0, stream>>>(
        bufB, W2, b2, dinv, bufA, N);  // bufA = h2

    // ---- layer 3: 128->96 (*dinv), then aggregate at F=96 (+b3) -> out ----
    transform_kernel<128, 96, false, false, true><<<tb, 8 * (96 / 4), 0, stream>>>(
        bufA, W3, nullptr, dinv, bufB, N);  // bufB = hw3s (scaled)
    gather_kernel<96, true><<<cdiv(N * 24, BLOCK), BLOCK, 0, stream>>>(
        row_ptr, deg, csr_src, dinv, bufB, b3, out, N);
}

// Round 5
// 471.379 us; speedup vs baseline: 14.9086x; 1.1664x over previous
//
#include <hip/hip_runtime.h>
#include <hip/hip_bf16.h>

// GCN 3-layer: x(N,12) -> 64 -> 128 -> 96, symmetric normalization + self loops.
// N=100000, E=1600000.
//
// R2: CSR + pull-gather (7028 -> 1364 us).
// R3: register-tiled 4x4-microtile transform (1364 -> 693 us).
// R4: associativity reorder (aggregate at 12/64/96) + prescaled rows (693 -> 550 us).
// R5: two-phase bucketed CSR build. The one-pass scatter wrote random 4B
//     entries from all XCDs -> 16x line-bounce write amplification (105 MB,
//     127 us). Phase A bins (s,d) pairs by dst/512 with coalesced-run writes;
//     Phase B scatters each bucket inside its own ~33 KB L2-resident window
//     from a single block.

static inline int cdiv(int a, int b) { return (a + b - 1) / b; }
constexpr int BLOCK = 256;
constexpr int BSHIFT = 9;                  // 512 nodes per bucket
constexpr int BNODES = 1 << BSHIFT;

// ---------------- CSR build ----------------

__global__ void zero_int_kernel(int* __restrict__ p, int n) {
    int i = blockIdx.x * blockDim.x + threadIdx.x;
    if (i < n) p[i] = 0;
}

__global__ void hist_kernel(const int* __restrict__ dst, int E, int* __restrict__ deg) {
    int e = blockIdx.x * blockDim.x + threadIdx.x;
    if (e < E) atomicAdd(&deg[dst[e]], 1);
}

// dinv includes the self loop: deg_norm = indeg + 1
__global__ void dinv_kernel(const int* __restrict__ deg, float* __restrict__ dinv, int N) {
    int i = blockIdx.x * blockDim.x + threadIdx.x;
    if (i < N) dinv[i] = rsqrtf((float)deg[i] + 1.0f);
}

// per-block exclusive scan (Hillis-Steele in LDS), emit block sums
__global__ void scan_block_kernel(const int* __restrict__ deg, int* __restrict__ row_ptr,
                                  int* __restrict__ bsum, int N) {
    __shared__ int tmp[BLOCK];
    int i = blockIdx.x * BLOCK + threadIdx.x;
    int v = (i < N) ? deg[i] : 0;
    tmp[threadIdx.x] = v;
    __syncthreads();
    for (int off = 1; off < BLOCK; off <<= 1) {
        int add = (threadIdx.x >= off) ? tmp[threadIdx.x - off] : 0;
        __syncthreads();
        tmp[threadIdx.x] += add;
        __syncthreads();
    }
    if (i < N) row_ptr[i] = tmp[threadIdx.x] - v;  // exclusive
    if (threadIdx.x == BLOCK - 1) bsum[blockIdx.x] = tmp[BLOCK - 1];
}

// single-block exclusive scan of block sums (nb <= 1024)
__global__ void scan_sums_kernel(int* __restrict__ bsum, int nb) {
    __shared__ int tmp[1024];
    int v = (threadIdx.x < nb) ? bsum[threadIdx.x] : 0;
    tmp[threadIdx.x] = v;
    __syncthreads();
    for (int off = 1; off < 1024; off <<= 1) {
        int add = (threadIdx.x >= off) ? tmp[threadIdx.x - off] : 0;
        __syncthreads();
        tmp[threadIdx.x] += add;
        __syncthreads();
    }
    if (threadIdx.x < nb) bsum[threadIdx.x] = tmp[threadIdx.x] - v;
}

__global__ void finalize_scan_kernel(int* __restrict__ row_ptr, const int* __restrict__ bsum,
                                     int N) {
    int i = blockIdx.x * BLOCK + threadIdx.x;
    if (i < N) row_ptr[i] += bsum[blockIdx.x];
}

// gcursor[b] = row_ptr[b*512]  (bucket b's CSR region start)
__global__ void bucket_init_kernel(const int* __restrict__ row_ptr, int* __restrict__ gcursor,
                                   int NB) {
    int b = blockIdx.x * blockDim.x + threadIdx.x;
    if (b < NB) gcursor[b] = row_ptr[b << BSHIFT];
}

// Phase A: bin edges by dst bucket. Each block handles CHUNK edges; writes
// (s,d) pairs in contiguous runs per (block,bucket) via global range reserve.
template <int CHUNK>
__global__ void bin_edges_kernel(const int* __restrict__ ei, int E,
                                 int* __restrict__ gcursor, int2* __restrict__ binned,
                                 int NB) {
    __shared__ int cnt[256], base[256], rk[256];   // NB <= 256
    for (int i = threadIdx.x; i < NB; i += blockDim.x) { cnt[i] = 0; rk[i] = 0; }
    __syncthreads();
    const int e0 = blockIdx.x * CHUNK;
    const int e1 = min(e0 + CHUNK, E);
    for (int e = e0 + threadIdx.x; e < e1; e += blockDim.x)
        atomicAdd(&cnt[ei[E + e] >> BSHIFT], 1);
    __syncthreads();
    for (int i = threadIdx.x; i < NB; i += blockDim.x)
        base[i] = atomicAdd(&gcursor[i], cnt[i]);
    __syncthreads();
    for (int e = e0 + threadIdx.x; e < e1; e += blockDim.x) {
        int s = ei[e], d = ei[E + e];
        int b = d >> BSHIFT;
        int r = atomicAdd(&rk[b], 1);
        binned[base[b] + r] = make_int2(s, d);
    }
}

// Phase B: one block per bucket; scatter within the bucket's CSR window
// using LDS cursors seeded from row_ptr. All writes XCD-local + L2-resident.
__global__ void csr_fill_kernel(const int* __restrict__ row_ptr, const int2* __restrict__ binned,
                                int* __restrict__ csr_src, int N, int E) {
    __shared__ int cur[BNODES];
    const int node0 = blockIdx.x << BSHIFT;
    const int nn = min(BNODES, N - node0);
    for (int j = threadIdx.x; j < nn; j += blockDim.x)
        cur[j] = row_ptr[node0 + j];
    __syncthreads();
    const int start = row_ptr[node0];
    const int end = (node0 + BNODES >= N) ? E : row_ptr[node0 + BNODES];
    for (int e = start + threadIdx.x; e < end; e += blockDim.x) {
        int2 sd = binned[e];
        int pos = atomicAdd(&cur[sd.y - node0], 1);
        csr_src[pos] = sd.x;
    }
}

// xs[i,:] = x[i,:] * dinv[i]   (F=12: 3 float4 chunks per row)
__global__ void prescale_kernel(const float* __restrict__ x, const float* __restrict__ dinv,
                                float* __restrict__ xs, int N) {
    int t = blockIdx.x * blockDim.x + threadIdx.x;
    if (t >= N * 3) return;
    int i = t / 3;
    float di = dinv[i];
    float4 v = ((const float4*)x)[t];
    v.x *= di; v.y *= di; v.z *= di; v.w *= di;
    ((float4*)xs)[t] = v;
}

// ---------------- dense transform (register-tiled) ----------------

__device__ __forceinline__ void fma4(float4& acc, float s, const float4& w) {
    acc.x = fmaf(s, w.x, acc.x);
    acc.y = fmaf(s, w.y, acc.y);
    acc.z = fmaf(s, w.z, acc.z);
    acc.w = fmaf(s, w.w, acc.w);
}

// Each thread computes a 4-row x 4-col microtile of out = h @ W, with
// optional epilogue: +bias, relu, *dinv[row]. Block covers 32 rows x OUT.
template <int IN, int OUT, bool HAS_BIAS, bool RELU, bool SCALE>
__global__ void transform_kernel(const float* __restrict__ h, const float* __restrict__ W,
                                 const float* __restrict__ bias, const float* __restrict__ dinv,
                                 float* __restrict__ out, int N) {
    constexpr int CG = OUT / 4;        // col groups
    constexpr int THREADS = 8 * CG;    // 8 row groups of 4 rows
    __shared__ float Ws[IN * OUT];
    for (int i = threadIdx.x; i < IN * OUT / 4; i += THREADS)
        ((float4*)Ws)[i] = ((const float4*)W)[i];
    __syncthreads();

    const int c0 = (threadIdx.x % CG) * 4;
    const int r0 = blockIdx.x * 32 + (threadIdx.x / CG) * 4;
    if (r0 >= N) return;  // N % 32 == 0

    const float* __restrict__ hr = h + (size_t)r0 * IN;
    float4 acc[4];
#pragma unroll
    for (int i = 0; i < 4; ++i) acc[i] = make_float4(0.f, 0.f, 0.f, 0.f);

#pragma unroll
    for (int k = 0; k < IN; k += 4) {
        float4 a[4];
#pragma unroll
        for (int i = 0; i < 4; ++i) a[i] = *(const float4*)(hr + (size_t)i * IN + k);
        const float4 w0 = *(const float4*)(Ws + (k + 0) * OUT + c0);
        const float4 w1 = *(const float4*)(Ws + (k + 1) * OUT + c0);
        const float4 w2 = *(const float4*)(Ws + (k + 2) * OUT + c0);
        const float4 w3 = *(const float4*)(Ws + (k + 3) * OUT + c0);
#pragma unroll
        for (int i = 0; i < 4; ++i) {
            fma4(acc[i], a[i].x, w0);
            fma4(acc[i], a[i].y, w1);
            fma4(acc[i], a[i].z, w2);
            fma4(acc[i], a[i].w, w3);
        }
    }

    float4 bb = make_float4(0.f, 0.f, 0.f, 0.f);
    if (HAS_BIAS) bb = *(const float4*)(bias + c0);
#pragma unroll
    for (int i = 0; i < 4; ++i) {
        float4 r = acc[i];
        if (HAS_BIAS) { r.x += bb.x; r.y += bb.y; r.z += bb.z; r.w += bb.w; }
        if (RELU) {
            r.x = fmaxf(r.x, 0.f); r.y = fmaxf(r.y, 0.f);
            r.z = fmaxf(r.z, 0.f); r.w = fmaxf(r.w, 0.f);
        }
        if (SCALE) {
            float di = dinv[r0 + i];
            r.x *= di; r.y *= di; r.z *= di; r.w *= di;
        }
        *(float4*)(out + (size_t)(r0 + i) * OUT + c0) = r;
    }
}

// ---------------- pull gather ----------------

// hws rows are pre-scaled by dinv[src].
// out[i, f0:f0+4] = dinv[i] * (hws[i] + sum_{s in CSR[i]} hws[s]) (+ b)
template <int F, bool HAS_BIAS>
__global__ void gather_kernel(const int* __restrict__ row_ptr, const int* __restrict__ deg,
                              const int* __restrict__ csr_src,
                              const float* __restrict__ dinv, const float* __restrict__ hws,
                              const float* __restrict__ b, float* __restrict__ out, int N) {
    constexpr int TPN = F / 4;  // threads per node
    int t = blockIdx.x * blockDim.x + threadIdx.x;
    if (t >= N * TPN) return;
    int i = t / TPN;
    int c = t - i * TPN;
    int f0 = c * 4;

    const int* __restrict__ sp = csr_src + row_ptr[i];
    int n = deg[i];
    float4 acc = *(const float4*)(hws + (size_t)i * F + f0);  // self loop

    int k = 0;
    for (; k + 4 <= n; k += 4) {
        int s0 = sp[k + 0], s1 = sp[k + 1], s2 = sp[k + 2], s3 = sp[k + 3];
        const float4 v0 = *(const float4*)(hws + (size_t)s0 * F + f0);
        const float4 v1 = *(const float4*)(hws + (size_t)s1 * F + f0);
        const float4 v2 = *(const float4*)(hws + (size_t)s2 * F + f0);
        const float4 v3 = *(const float4*)(hws + (size_t)s3 * F + f0);
        acc.x += (v0.x + v1.x) + (v2.x + v3.x);
        acc.y += (v0.y + v1.y) + (v2.y + v3.y);
        acc.z += (v0.z + v1.z) + (v2.z + v3.z);
        acc.w += (v0.w + v1.w) + (v2.w + v3.w);
    }
    for (; k < n; ++k) {
        int s = sp[k];
        const float4 v = *(const float4*)(hws + (size_t)s * F + f0);
        acc.x += v.x; acc.y += v.y; acc.z += v.z; acc.w += v.w;
    }

    float di = dinv[i];
    float4 r;
    if (HAS_BIAS) {
        const float4 bb = *(const float4*)(b + f0);
        r.x = fmaf(acc.x, di, bb.x);
        r.y = fmaf(acc.y, di, bb.y);
        r.z = fmaf(acc.z, di, bb.z);
        r.w = fmaf(acc.w, di, bb.w);
    } else {
        r.x = acc.x * di; r.y = acc.y * di; r.z = acc.z * di; r.w = acc.w * di;
    }
    *(float4*)(out + (size_t)i * F + f0) = r;
}

// ---------------- launch ----------------

extern "C" void kernel_launch(void* const* d_in, const int* in_sizes, int n_in,
                              void* d_out, int out_size, void* d_ws, size_t ws_size,
                              hipStream_t stream) {
    const float* x  = (const float*)d_in[0];
    const int*   ei = (const int*)d_in[1];  // (2,E): row0=src, row1=dst
    const float* W1 = (const float*)d_in[2];
    const float* b1 = (const float*)d_in[3];
    const float* W2 = (const float*)d_in[4];
    const float* b2 = (const float*)d_in[5];
    const float* W3 = (const float*)d_in[6];
    const float* b3 = (const float*)d_in[7];
    float* out = (float*)d_out;

    const int N = in_sizes[0] / 12;
    const int E = in_sizes[1] / 2;
    const int nb = cdiv(N, BLOCK);
    const int NB = cdiv(N, BNODES);  // 196 dst buckets (<=256)

    // workspace layout
    char* ws = (char*)d_ws;
    int*   deg     = (int*)ws;    ws += (size_t)N * sizeof(int);
    int*   row_ptr = (int*)ws;    ws += (size_t)N * sizeof(int);
    int*   gcursor = (int*)ws;    ws += 256 * sizeof(int);
    int*   bsum    = (int*)ws;    ws += 1024 * sizeof(int);
    float* dinv    = (float*)ws;  ws += (size_t)N * sizeof(float);
    int*   csr_src = (int*)ws;    ws += (size_t)E * sizeof(int);
    float* bufA    = (float*)ws;  ws += (size_t)N * 128 * sizeof(float);  // xs / h1s / h2
    float* bufB    = (float*)ws;                                          // aggx / agg1 / hw3s
    int2*  binned  = (int2*)bufB;  // aliased: consumed by csr_fill before gathers run

    // ---- CSR build (shared across layers) ----
    zero_int_kernel<<<nb, BLOCK, 0, stream>>>(deg, N);
    hist_kernel<<<cdiv(E, BLOCK), BLOCK, 0, stream>>>(ei + E, E, deg);
    dinv_kernel<<<nb, BLOCK, 0, stream>>>(deg, dinv, N);
    scan_block_kernel<<<nb, BLOCK, 0, stream>>>(deg, row_ptr, bsum, N);
    scan_sums_kernel<<<1, 1024, 0, stream>>>(bsum, nb);
    finalize_scan_kernel<<<nb, BLOCK, 0, stream>>>(row_ptr, bsum, N);
    bucket_init_kernel<<<1, 256, 0, stream>>>(row_ptr, gcursor, NB);
    bin_edges_kernel<4096><<<cdiv(E, 4096), BLOCK, 0, stream>>>(ei, E, gcursor, binned, NB);
    csr_fill_kernel<<<NB, BLOCK, 0, stream>>>(row_ptr, binned, csr_src, N, E);

    const int tb = cdiv(N, 32);  // transform blocks

    // ---- layer 1: aggregate at F=12, then 12->64 (+b1, relu, *dinv) ----
    prescale_kernel<<<cdiv(N * 3, BLOCK), BLOCK, 0, stream>>>(x, dinv, bufA, N);
    gather_kernel<12, false><<<cdiv(N * 3, BLOCK), BLOCK, 0, stream>>>(
        row_ptr, deg, csr_src, dinv, bufA, nullptr, bufB, N);
    transform_kernel<12, 64, true, true, true><<<tb, 8 * (64 / 4), 0, stream>>>(
        bufB, W1, b1, dinv, bufA, N);  // bufA = h1s (scaled)

    // ---- layer 2: aggregate at F=64, then 64->128 (+b2, relu) ----
    gather_kernel<64, false><<<cdiv(N * 16, BLOCK), BLOCK, 0, stream>>>(
        row_ptr, deg, csr_src, dinv, bufA, nullptr, bufB, N);
    transform_kernel<64, 128, true, true, false><<<tb, 8 * (128 / 4), 0, stream>>>(
        bufB, W2, b2, dinv, bufA, N);  // bufA = h2

    // ---- layer 3: 128->96 (*dinv), then aggregate at F=96 (+b3) -> out ----
    transform_kernel<128, 96, false, false, true><<<tb, 8 * (96 / 4), 0, stream>>>(
        bufA, W3, nullptr, dinv, bufB, N);  // bufB = hw3s (scaled)
    gather_kernel<96, true><<<cdiv(N * 24, BLOCK), BLOCK, 0, stream>>>(
        row_ptr, deg, csr_src, dinv, bufB, b3, out, N);
}